// Round 1
// baseline (210.509 us; speedup 1.0000x reference)
//
#include <hip/hip_runtime.h>
#include <hip/hip_bf16.h>
#include <stdint.h>
#include <stddef.h>

#define T_TOK 2048
#define DDIM  2048
#define FDIM  768
#define NEXP  8
#define NSLOT (T_TOK*2)

typedef __attribute__((ext_vector_type(4))) float  f32x4;
typedef __attribute__((ext_vector_type(8))) short  bf16x8;

// ---- workspace layout (bytes) ----
static constexpr size_t WS_CNT  = 0;                                  // 8 int
static constexpr size_t WS_BASE = 64;                                 // 8 int
static constexpr size_t WS_TOK  = 256;                                // [E][T] int
static constexpr size_t WS_WT   = WS_TOK + (size_t)NEXP*T_TOK*4;      // [E][T] float
static constexpr size_t WS_XB   = WS_WT  + (size_t)NEXP*T_TOK*4;      // [T][D] bf16
static constexpr size_t WS_W1T  = WS_XB  + (size_t)T_TOK*DDIM*2;      // [E][F][D] bf16
static constexpr size_t WS_W3T  = WS_W1T + (size_t)NEXP*FDIM*DDIM*2;  // [E][F][D] bf16
static constexpr size_t WS_W2T  = WS_W3T + (size_t)NEXP*FDIM*DDIM*2;  // [E][D][F] bf16
static constexpr size_t WS_ACT  = WS_W2T + (size_t)NEXP*DDIM*FDIM*2;  // [NSLOT][F] bf16
// end ~90.3 MB

__device__ __forceinline__ void gl_lds16(const void* g, void* l) {
  __builtin_amdgcn_global_load_lds((const __attribute__((address_space(1))) void*)g,
                                   (__attribute__((address_space(3))) void*)l, 16, 0, 0);
}

__device__ __forceinline__ f32x4 mfma_bf16(bf16x8 a, bf16x8 b, f32x4 c) {
  asm("v_mfma_f32_16x16x32_bf16 %0, %1, %2, %0" : "+v"(c) : "v"(a), "v"(b));
  return c;
}

// ---- x fp32 -> bf16 ----
__global__ __launch_bounds__(256) void k_cast_x(const float* __restrict__ x,
                                                __hip_bfloat16* __restrict__ xb) {
  size_t i = ((size_t)blockIdx.x*256 + threadIdx.x) * 8;
  float4 a = *(const float4*)(x + i);
  float4 b = *(const float4*)(x + i + 4);
  union { __hip_bfloat16 h[8]; int4 v; } u;
  u.h[0] = __float2bfloat16(a.x); u.h[1] = __float2bfloat16(a.y);
  u.h[2] = __float2bfloat16(a.z); u.h[3] = __float2bfloat16(a.w);
  u.h[4] = __float2bfloat16(b.x); u.h[5] = __float2bfloat16(b.y);
  u.h[6] = __float2bfloat16(b.z); u.h[7] = __float2bfloat16(b.w);
  *(int4*)(xb + i) = u.v;
}

// ---- src [E][R][C] fp32 -> dst [E][C][R] bf16 ----
__global__ __launch_bounds__(256) void k_transpose_cast(const float* __restrict__ src,
                                                        __hip_bfloat16* __restrict__ dst,
                                                        int R, int C) {
  __shared__ float tile[32][33];
  const float* s = src + (size_t)blockIdx.z*R*C;
  __hip_bfloat16* d = dst + (size_t)blockIdx.z*C*R;
  int c0 = blockIdx.x*32, r0 = blockIdx.y*32;
  int tx = threadIdx.x, ty = threadIdx.y;
#pragma unroll
  for (int i = 0; i < 32; i += 8)
    tile[ty+i][tx] = s[(size_t)(r0+ty+i)*C + (c0+tx)];
  __syncthreads();
#pragma unroll
  for (int i = 0; i < 32; i += 8)
    d[(size_t)(c0+ty+i)*R + (r0+tx)] = __float2bfloat16(tile[tx][ty+i]);
}

// ---- router: logits, top-2, renorm, scatter to expert lists ----
__global__ __launch_bounds__(256) void k_router(const float* __restrict__ x,
                                                const float* __restrict__ gw,
                                                int* __restrict__ cnt,
                                                int* __restrict__ tok,
                                                float* __restrict__ wt) {
  int wave = threadIdx.x >> 6, lane = threadIdx.x & 63;
  int t = blockIdx.x*4 + wave;
  const float* xr = x + (size_t)t*DDIM;
  float acc[NEXP] = {0.f,0.f,0.f,0.f,0.f,0.f,0.f,0.f};
  for (int i = 0; i < DDIM/64; i++) {
    int dd = lane + i*64;
    float xv = xr[dd];
    float4 g0 = *(const float4*)(gw + dd*8);
    float4 g1 = *(const float4*)(gw + dd*8 + 4);
    acc[0] += xv*g0.x; acc[1] += xv*g0.y; acc[2] += xv*g0.z; acc[3] += xv*g0.w;
    acc[4] += xv*g1.x; acc[5] += xv*g1.y; acc[6] += xv*g1.z; acc[7] += xv*g1.w;
  }
#pragma unroll
  for (int off = 32; off >= 1; off >>= 1) {
#pragma unroll
    for (int e = 0; e < NEXP; e++) acc[e] += __shfl_xor(acc[e], off, 64);
  }
  if (lane == 0) {
    int i1 = 0; float m1 = acc[0];
#pragma unroll
    for (int e = 1; e < NEXP; e++) if (acc[e] > m1) { m1 = acc[e]; i1 = e; }
    int i2 = -1; float m2 = -1e30f;
#pragma unroll
    for (int e = 0; e < NEXP; e++) if (e != i1 && acc[e] > m2) { m2 = acc[e]; i2 = e; }
    float r  = expf(m2 - m1);          // p2/p1
    float wa = 1.f/(1.f + r);
    float wb = r/(1.f + r);
    int p1 = atomicAdd(&cnt[i1], 1);
    tok[i1*T_TOK + p1] = t;  wt[i1*T_TOK + p1] = wa;
    int p2 = atomicAdd(&cnt[i2], 1);
    tok[i2*T_TOK + p2] = t;  wt[i2*T_TOK + p2] = wb;
  }
}

__global__ void k_prefix(const int* __restrict__ cnt, int* __restrict__ base) {
  if (threadIdx.x == 0) {
    int s = 0;
    for (int e = 0; e < NEXP; e++) { base[e] = s; s += cnt[e]; }
  }
}

// ---- phase 1: per-expert grouped GEMM: g = Xe@W1, u = Xe@W3, act = silu(g)*u ----
__global__ __launch_bounds__(256,4) void k_ffn1(
    const __hip_bfloat16* __restrict__ xb,
    const __hip_bfloat16* __restrict__ w1t,   // [E][F][D]
    const __hip_bfloat16* __restrict__ w3t,   // [E][F][D]
    const int* __restrict__ cnt, const int* __restrict__ base,
    const int* __restrict__ tok,
    __hip_bfloat16* __restrict__ act) {       // [NSLOT][F]
  int e  = blockIdx.z;
  int ne = cnt[e];
  int m0 = blockIdx.y * 64;
  if (m0 >= ne) return;
  int n0 = blockIdx.x * 64;
  int tid = threadIdx.x, wave = tid >> 6, lane = tid & 63;

  __shared__ __hip_bfloat16 sA[64*64], sB1[64*64], sB3[64*64];

  // staging: wave covers rows [16w,16w+16) of each 64x64 bf16 tile as 2x 1KB chunks.
  // LDS dest linear; global source pre-XOR-swizzled (G21: both-sides-or-neither).
  const __hip_bfloat16 *aptr[2], *b1p[2], *b3p[2];
  int ldsoff[2];
#pragma unroll
  for (int c = 0; c < 2; c++) {
    int r  = wave*16 + c*8 + (lane>>3);
    int kb = ((lane&7)*16) ^ ((r&7)<<4);
    int slot = m0 + r; if (slot >= ne) slot = ne - 1;
    int t = tok[e*T_TOK + slot];
    aptr[c] = xb  + (size_t)t*DDIM + (kb>>1);
    b1p[c]  = w1t + ((size_t)e*FDIM + n0 + r)*DDIM + (kb>>1);
    b3p[c]  = w3t + ((size_t)e*FDIM + n0 + r)*DDIM + (kb>>1);
    ldsoff[c] = (wave*16 + c*8)*128;
  }

  f32x4 accg[2][2], accu[2][2];
#pragma unroll
  for (int a = 0; a < 2; a++)
#pragma unroll
    for (int b = 0; b < 2; b++) {
      accg[a][b] = (f32x4){0.f,0.f,0.f,0.f};
      accu[a][b] = (f32x4){0.f,0.f,0.f,0.f};
    }

  int wr = wave >> 1, wc = wave & 1;

  for (int kt = 0; kt < DDIM/64; ++kt) {
#pragma unroll
    for (int c = 0; c < 2; c++) {
      gl_lds16(aptr[c] + kt*64, (char*)sA  + ldsoff[c]);
      gl_lds16(b1p[c]  + kt*64, (char*)sB1 + ldsoff[c]);
      gl_lds16(b3p[c]  + kt*64, (char*)sB3 + ldsoff[c]);
    }
    __syncthreads();
#pragma unroll
    for (int ks = 0; ks < 2; ks++) {
      bf16x8 a_[2], b1_[2], b3_[2];
#pragma unroll
      for (int mf = 0; mf < 2; mf++) {
        int r = wr*32 + mf*16 + (lane&15);
        int off = r*128 + (((ks*64) + ((lane>>4)<<4)) ^ ((r&7)<<4));
        a_[mf] = *(const bf16x8*)((const char*)sA + off);
      }
#pragma unroll
      for (int nf = 0; nf < 2; nf++) {
        int r = wc*32 + nf*16 + (lane&15);
        int off = r*128 + (((ks*64) + ((lane>>4)<<4)) ^ ((r&7)<<4));
        b1_[nf] = *(const bf16x8*)((const char*)sB1 + off);
        b3_[nf] = *(const bf16x8*)((const char*)sB3 + off);
      }
#pragma unroll
      for (int mf = 0; mf < 2; mf++)
#pragma unroll
        for (int nf = 0; nf < 2; nf++) {
          accg[mf][nf] = mfma_bf16(a_[mf], b1_[nf], accg[mf][nf]);
          accu[mf][nf] = mfma_bf16(a_[mf], b3_[nf], accu[mf][nf]);
        }
    }
    __syncthreads();
  }

  int be = base[e];
#pragma unroll
  for (int mf = 0; mf < 2; mf++)
#pragma unroll
    for (int nf = 0; nf < 2; nf++)
#pragma unroll
      for (int j = 0; j < 4; j++) {
        int slot = m0 + wr*32 + mf*16 + (lane>>4)*4 + j;  // C/D: row=(lane>>4)*4+j
        if (slot < ne) {
          int f = n0 + wc*32 + nf*16 + (lane&15);         // C/D: col=lane&15
          float g = accg[mf][nf][j], u = accu[mf][nf][j];
          float s = g / (1.f + __expf(-g));
          act[(size_t)(be+slot)*FDIM + f] = __float2bfloat16(s*u);
        }
      }
}

// ---- phase 2: Y = act @ W2, scaled scatter-add into y ----
__global__ __launch_bounds__(256,4) void k_ffn2(
    const __hip_bfloat16* __restrict__ act,   // [NSLOT][F]
    const __hip_bfloat16* __restrict__ w2t,   // [E][D][F]
    const int* __restrict__ cnt, const int* __restrict__ base,
    const int* __restrict__ tok, const float* __restrict__ wt,
    float* __restrict__ y) {
  int e  = blockIdx.z;
  int ne = cnt[e];
  int m0 = blockIdx.y * 64;
  if (m0 >= ne) return;
  int n0 = blockIdx.x * 64;
  int tid = threadIdx.x, wave = tid >> 6, lane = tid & 63;
  int be = base[e];

  __shared__ __hip_bfloat16 sA[64*64], sB[64*64];

  const __hip_bfloat16 *aptr[2], *bp[2];
  int ldsoff[2];
#pragma unroll
  for (int c = 0; c < 2; c++) {
    int r  = wave*16 + c*8 + (lane>>3);
    int kb = ((lane&7)*16) ^ ((r&7)<<4);
    int slot = m0 + r; if (slot >= ne) slot = ne - 1;
    aptr[c] = act + (size_t)(be+slot)*FDIM + (kb>>1);
    bp[c]   = w2t + ((size_t)e*DDIM + n0 + r)*FDIM + (kb>>1);
    ldsoff[c] = (wave*16 + c*8)*128;
  }

  f32x4 acc[2][2];
#pragma unroll
  for (int a = 0; a < 2; a++)
#pragma unroll
    for (int b = 0; b < 2; b++) acc[a][b] = (f32x4){0.f,0.f,0.f,0.f};

  int wr = wave >> 1, wc = wave & 1;

  for (int kt = 0; kt < FDIM/64; ++kt) {
#pragma unroll
    for (int c = 0; c < 2; c++) {
      gl_lds16(aptr[c] + kt*64, (char*)sA + ldsoff[c]);
      gl_lds16(bp[c]   + kt*64, (char*)sB + ldsoff[c]);
    }
    __syncthreads();
#pragma unroll
    for (int ks = 0; ks < 2; ks++) {
      bf16x8 a_[2], b_[2];
#pragma unroll
      for (int mf = 0; mf < 2; mf++) {
        int r = wr*32 + mf*16 + (lane&15);
        int off = r*128 + (((ks*64) + ((lane>>4)<<4)) ^ ((r&7)<<4));
        a_[mf] = *(const bf16x8*)((const char*)sA + off);
      }
#pragma unroll
      for (int nf = 0; nf < 2; nf++) {
        int r = wc*32 + nf*16 + (lane&15);
        int off = r*128 + (((ks*64) + ((lane>>4)<<4)) ^ ((r&7)<<4));
        b_[nf] = *(const bf16x8*)((const char*)sB + off);
      }
#pragma unroll
      for (int mf = 0; mf < 2; mf++)
#pragma unroll
        for (int nf = 0; nf < 2; nf++)
          acc[mf][nf] = mfma_bf16(a_[mf], b_[nf], acc[mf][nf]);
    }
    __syncthreads();
  }

#pragma unroll
  for (int mf = 0; mf < 2; mf++)
#pragma unroll
    for (int nf = 0; nf < 2; nf++)
#pragma unroll
      for (int j = 0; j < 4; j++) {
        int slot = m0 + wr*32 + mf*16 + (lane>>4)*4 + j;
        if (slot < ne) {
          int d  = n0 + wc*32 + nf*16 + (lane&15);
          int t  = tok[e*T_TOK + slot];
          float w = wt[e*T_TOK + slot];
          unsafeAtomicAdd(y + (size_t)t*DDIM + d, w*acc[mf][nf][j]);
        }
      }
}

extern "C" void kernel_launch(void* const* d_in, const int* in_sizes, int n_in,
                              void* d_out, int out_size, void* d_ws, size_t ws_size,
                              hipStream_t stream) {
  const float* x  = (const float*)d_in[0];
  const float* gw = (const float*)d_in[1];
  const float* w1 = (const float*)d_in[2];
  const float* w2 = (const float*)d_in[3];
  const float* w3 = (const float*)d_in[4];
  float* y = (float*)d_out;
  char* ws = (char*)d_ws;

  int*   cnt  = (int*)  (ws + WS_CNT);
  int*   basep= (int*)  (ws + WS_BASE);
  int*   tok  = (int*)  (ws + WS_TOK);
  float* wtb  = (float*)(ws + WS_WT);
  __hip_bfloat16* xb   = (__hip_bfloat16*)(ws + WS_XB);
  __hip_bfloat16* w1t  = (__hip_bfloat16*)(ws + WS_W1T);
  __hip_bfloat16* w3t  = (__hip_bfloat16*)(ws + WS_W3T);
  __hip_bfloat16* w2t  = (__hip_bfloat16*)(ws + WS_W2T);
  __hip_bfloat16* actb = (__hip_bfloat16*)(ws + WS_ACT);

  hipMemsetAsync(ws + WS_CNT, 0, 256, stream);
  hipMemsetAsync(d_out, 0, (size_t)out_size * sizeof(float), stream);

  k_cast_x<<<(T_TOK*DDIM)/(256*8), 256, 0, stream>>>(x, xb);

  dim3 tb(32, 8);
  k_transpose_cast<<<dim3(FDIM/32, DDIM/32, NEXP), tb, 0, stream>>>(w1, w1t, DDIM, FDIM);
  k_transpose_cast<<<dim3(FDIM/32, DDIM/32, NEXP), tb, 0, stream>>>(w3, w3t, DDIM, FDIM);
  k_transpose_cast<<<dim3(DDIM/32, FDIM/32, NEXP), tb, 0, stream>>>(w2, w2t, FDIM, DDIM);

  k_router<<<T_TOK/4, 256, 0, stream>>>(x, gw, cnt, tok, wtb);
  k_prefix<<<1, 64, 0, stream>>>(cnt, basep);

  k_ffn1<<<dim3(FDIM/64, T_TOK/64, NEXP), 256, 0, stream>>>(xb, w1t, w3t, cnt, basep, tok, actb);
  k_ffn2<<<dim3(DDIM/64, T_TOK/64, NEXP), 256, 0, stream>>>(actb, w2t, cnt, basep, tok, wtb, y);
}